// Round 2
// baseline (697.719 us; speedup 1.0000x reference)
//
#include <hip/hip_runtime.h>

#define BETA 0.96f
#define NB 4096
#define NI 96
#define NH 50
#define NO 2
#define NT 250
#define WSTRIDE 64          // padded row stride of transposed W1
#define G 8                 // x prefetch group size
#define NBLK (NI / G)       // 12

// One-time (per launch) transpose: W1[H][I] -> w1t[I][WSTRIDE], zero-padded.
// Lets the main kernel read W1 rows as contiguous wave-uniform loads.
__global__ void w1_transpose_kernel(const float* __restrict__ W1,
                                    float* __restrict__ w1t) {
    int idx = blockIdx.x * blockDim.x + threadIdx.x;
    if (idx >= NI * WSTRIDE) return;
    int i = idx >> 6;
    int h = idx & 63;
    w1t[idx] = (h < NH) ? W1[h * NI + i] : 0.0f;
}

// wave = one batch element b. Phase A (lanes = t): cur1 GEMM, coalesced x.
// Phase B (lanes = h): serial LIF over t via 13KB LDS bounce, ballot -> spike mask.
// Phase C (lanes = t): mask-dot with W2, Kogge-Stone beta-weighted scan for mem2.
__global__ __launch_bounds__(64, 3) void snn_fused_kernel(
    const float* __restrict__ x,
    const float* __restrict__ w1t,
    const float* __restrict__ W2,
    float* __restrict__ out)
{
    __shared__ float cur1_lds[NH][65];   // [h][t], +1 pad -> <=2-way banks (free)
    const int b = blockIdx.x;
    const int lane = threadIdx.x;

    float mem1 = 0.0f;                   // lane = h role, persistent across chunks
    float m2a = 0.0f, m2b = 0.0f;        // mem2 carry (wave-uniform)
    // beta^(lane+1), log2(0.96) = -0.05889368905...
    const float bpow = exp2f((float)(lane + 1) * -0.05889368905356867f);
    const int hcl = (lane < NH) ? lane : (NH - 1);

    const float* xrow_base = x + (size_t)b * (NI * NT);

    for (int c = 0; c < 4; ++c) {
        const int t0 = c * 64;
        const int TT = (NT - t0 < 64) ? (NT - t0) : 64;          // 64,64,64,58
        const int tl = (t0 + lane < NT) ? (t0 + lane) : (NT - 1); // clamped load t
        const float* xb = xrow_base + tl;

        // ---------------- Phase A: cur1[h] for my t, lanes = t ----------------
        float acc[NH];
        #pragma unroll
        for (int h = 0; h < NH; ++h) acc[h] = 0.0f;

        float xa[G], xc[G];
        #pragma unroll
        for (int g = 0; g < G; ++g) xa[g] = xb[g * NT];   // i = 0..7

        for (int blk = 0; blk < NBLK; blk += 2) {
            // prefetch block blk+1 (always valid: max i = 95)
            #pragma unroll
            for (int g = 0; g < G; ++g) xc[g] = xb[((blk + 1) * G + g) * NT];
            // consume block blk
            #pragma unroll
            for (int g = 0; g < G; ++g) {
                const float* w1row = w1t + (blk * G + g) * WSTRIDE; // wave-uniform
                const float xv = xa[g];
                #pragma unroll
                for (int h = 0; h < NH; ++h)
                    acc[h] = fmaf(xv, w1row[h], acc[h]);
            }
            // prefetch block blk+2 (clamp last)
            #pragma unroll
            for (int g = 0; g < G; ++g) {
                int i = (blk + 2) * G + g;
                if (i > NI - 1) i = NI - 1;
                xa[g] = xb[i * NT];
            }
            // consume block blk+1
            #pragma unroll
            for (int g = 0; g < G; ++g) {
                const float* w1row = w1t + ((blk + 1) * G + g) * WSTRIDE;
                const float xv = xc[g];
                #pragma unroll
                for (int h = 0; h < NH; ++h)
                    acc[h] = fmaf(xv, w1row[h], acc[h]);
            }
        }

        // ---------------- bounce cur1 to LDS: [h][t] ----------------
        #pragma unroll
        for (int h = 0; h < NH; ++h) cur1_lds[h][lane] = acc[h];
        // single wave owns this buffer: compiler-inserted lgkmcnt orders it

        // ---------------- Phase B: serial LIF, lanes = h ----------------
        unsigned vml = 0u, vmh = 0u;   // spike masks redistributed to lane = t
        for (int t = 0; t < TT; ++t) {
            const float cur = cur1_lds[hcl][t];
            const float base = fmaf(BETA, mem1, cur);
            // reset='zero': if previous mem crossed threshold, zero the base
            mem1 = (mem1 > 1.0f) ? 0.0f : base;
            const unsigned long long m = __ballot(mem1 > 1.0f); // spike bits by h
            // m is wave-uniform; lane t keeps it (predicated select, no writelane)
            const unsigned lo = (unsigned)(m & 0xffffffffull);
            const unsigned hi = (unsigned)(m >> 32);
            const bool mine = (lane == t);
            vml = mine ? lo : vml;
            vmh = mine ? hi : vmh;
        }

        // ---------------- Phase C: cur2 + mem2 scan, lanes = t ----------------
        float c2a = 0.0f, c2b = 0.0f;
        #pragma unroll
        for (int h = 0; h < NH; ++h) {
            const unsigned w = (h < 32) ? vml : vmh;
            const float bit = (float)((w >> (h & 31)) & 1u);
            c2a = fmaf(bit, W2[h], c2a);          // W2[0][h], wave-uniform
            c2b = fmaf(bit, W2[NH + h], c2b);     // W2[1][h]
        }
        // inclusive beta-weighted scan: s_t = sum_{s<=t} beta^(t-s) c_s
        float sa = c2a, sb = c2b;
        float bk = BETA;
        #pragma unroll
        for (int k = 1; k <= 32; k <<= 1) {
            const float pa = __shfl_up(sa, (unsigned)k, 64);
            const float pb = __shfl_up(sb, (unsigned)k, 64);
            if (lane >= k) {
                sa = fmaf(bk, pa, sa);
                sb = fmaf(bk, pb, sb);
            }
            bk *= bk;
        }
        const float outa = fmaf(bpow, m2a, sa);   // + beta^(lane+1) * carry
        const float outb = fmaf(bpow, m2b, sb);
        m2a = __shfl(outa, TT - 1, 64);           // carry = last valid t
        m2b = __shfl(outb, TT - 1, 64);
        if (lane < TT) {
            out[((size_t)b * NO + 0) * NT + t0 + lane] = outa;
            out[((size_t)b * NO + 1) * NT + t0 + lane] = outb;
        }
    }
}

extern "C" void kernel_launch(void* const* d_in, const int* in_sizes, int n_in,
                              void* d_out, int out_size, void* d_ws, size_t ws_size,
                              hipStream_t stream) {
    const float* x  = (const float*)d_in[0];
    const float* W1 = (const float*)d_in[1];
    const float* W2 = (const float*)d_in[2];
    float* out = (float*)d_out;
    float* w1t = (float*)d_ws;   // NI*WSTRIDE floats = 24.6 KB scratch

    hipLaunchKernelGGL(w1_transpose_kernel, dim3((NI * WSTRIDE + 255) / 256),
                       dim3(256), 0, stream, W1, w1t);
    hipLaunchKernelGGL(snn_fused_kernel, dim3(NB), dim3(64), 0, stream,
                       x, w1t, W2, out);
}